// Round 13
// baseline (253.514 us; speedup 1.0000x reference)
//
#include <hip/hip_runtime.h>
#include <hip/hip_bf16.h>

typedef short short8 __attribute__((ext_vector_type(8)));
typedef short short4b __attribute__((ext_vector_type(4)));
typedef float f32x4 __attribute__((ext_vector_type(4)));

#define GPTR(x) ((const __attribute__((address_space(1))) void*)(x))
#define LPTR(x) ((__attribute__((address_space(3))) void*)(x))

static __device__ __forceinline__ unsigned short f2bf(float f) {
  __hip_bfloat16 h = __float2bfloat16(f);
  return __builtin_bit_cast(unsigned short, h);
}
static __device__ __forceinline__ float bf2f(unsigned short u) {
  unsigned int v = ((unsigned int)u) << 16;
  return __builtin_bit_cast(float, v);
}
// raw v_exp_f32 (no libm guards)
static __device__ __forceinline__ float fexp2(float x) {
#if __has_builtin(__builtin_amdgcn_exp2f)
  return __builtin_amdgcn_exp2f(x);
#else
  return exp2f(x);
#endif
}
// truncating f32->bf16 (1 shift vs ~5-op RNE); P numerator only, ~-0.2% bias cancels in ratio
static __device__ __forceinline__ short bftrunc(float f) {
  return (short)(__builtin_bit_cast(unsigned int, f) >> 16);
}

// ---------------- block reduction helper ----------------
static __device__ __forceinline__ void block_reduce2(float& s, float& q) {
#pragma unroll
  for (int o = 32; o > 0; o >>= 1) { s += __shfl_down(s, o); q += __shfl_down(q, o); }
  __shared__ float rs[4], rq[4];
  int tid = threadIdx.x;
  if ((tid & 63) == 0) { rs[tid >> 6] = s; rq[tid >> 6] = q; }
  __syncthreads();
  if (tid == 0) {
    s = rs[0] + rs[1] + rs[2] + rs[3];
    q = rq[0] + rq[1] + rq[2] + rq[3];
  }
}

// ---------------- GN1 stats stage 1: 512 blocks ----------------
__global__ __launch_bounds__(256) void gn1_stats_kernel(const float* __restrict__ x,
                                                        float2* __restrict__ part1) {
  int bgc = blockIdx.x;  // (b*32+g)*8 + chunk
  const float4* base = (const float4*)x + (size_t)bgc * 1152;
  float s = 0.f, q = 0.f;
  for (int i = threadIdx.x; i < 1152; i += 256) {
    float4 v = base[i];
    s += v.x + v.y + v.z + v.w;
    q += v.x * v.x + v.y * v.y + v.z * v.z + v.w * v.w;
  }
  block_reduce2(s, q);
  if (threadIdx.x == 0) part1[bgc] = make_float2(s, q);
}

// ---------------- fused: tnorm (blocks 0..2303) + weight prep / mem-KV (blocks 2304..6431) ----------------
__global__ __launch_bounds__(256) void tnorm_prep_kernel(const float* __restrict__ x,
    const float* __restrict__ gw, const float* __restrict__ gb,
    const float2* __restrict__ part1, unsigned short* __restrict__ t,
    const float* __restrict__ wqkv, const float* __restrict__ wout,
    const float* __restrict__ memkv,
    unsigned short* __restrict__ wq, unsigned short* __restrict__ wo,
    unsigned short* __restrict__ Kb, unsigned short* __restrict__ Vt) {
  __shared__ float tile[32][33];
  int blk = blockIdx.x;
  if (blk < 2304) {
    int n0 = (blk % 72) * 32, c0 = ((blk / 72) & 15) * 32, b = blk / 1152;
    int g0 = c0 >> 4;
    float mu2[2], rs2[2];
#pragma unroll
    for (int gg = 0; gg < 2; gg++) {
      float s = 0.f, q = 0.f;
      const float2* p = part1 + (size_t)(b * 32 + g0 + gg) * 8;
#pragma unroll
      for (int k = 0; k < 8; k++) { float2 v = p[k]; s += v.x; q += v.y; }
      float mu = s / 36864.f;
      float var = q / 36864.f - mu * mu;
      mu2[gg] = mu;
      rs2[gg] = rsqrtf(var + 1e-5f);
    }
    int tx = threadIdx.x & 31, ty = threadIdx.x >> 5;
#pragma unroll
    for (int r = 0; r < 4; r++) {
      int c = c0 + ty + r * 8;
      tile[ty + r * 8][tx] = x[((size_t)(b * 512 + c)) * 2304 + n0 + tx];
    }
    __syncthreads();
    int gg = tx >> 4;
#pragma unroll
    for (int r = 0; r < 4; r++) {
      int n = n0 + ty + r * 8;
      int c = c0 + tx;
      float v = tile[tx][ty + r * 8];
      t[((size_t)(b * 2304 + n)) * 512 + c] = f2bf((v - mu2[gg]) * rs2[gg] * gw[c] + gb[c]);
    }
  } else {
    int i = (blk - 2304) * 256 + threadIdx.x;
    if (i < 786432) {
      wq[i] = f2bf(wqkv[i]);
    } else if (i < 1048576) {
      int j = i - 786432;
      wo[j] = f2bf(wout[j]);
    } else if (i < 1056768) {
      int tt = i - 1048576;  // (((s*2+b)*8+h)*4+j)*64+d
      int d = tt & 63, j = (tt >> 6) & 3, h = (tt >> 8) & 7, b = (tt >> 11) & 1, s = tt >> 12;
      unsigned short bv = f2bf(memkv[((s * 8 + h) * 64 + d) * 4 + j]);
      if (s == 0) Kb[((size_t)(b * 8 + h) * 2308 + j) * 64 + d] = bv;
      else        Vt[((size_t)(b * 8 + h) * 64 + d) * 2368 + j] = bv;
    }
  }
}

// ---------------- GEMM1: 64x128 tiles (864 blocks); Q pre-scaled by CS; V direct-transposed ----------------
__global__ __launch_bounds__(256) void gemm_qkv_kernel(
    const unsigned short* __restrict__ A, const unsigned short* __restrict__ Bw,
    unsigned short* __restrict__ Qb, unsigned short* __restrict__ Kb,
    unsigned short* __restrict__ Vt) {
  __shared__ __attribute__((aligned(16))) unsigned short As[64 * 32];
  __shared__ __attribute__((aligned(16))) unsigned short Bs[128 * 32];
  int m0 = blockIdx.x * 64, o0 = blockIdx.y * 128;
  int tid = threadIdx.x, lane = tid & 63, wave = tid >> 6;
  int quad = lane >> 4, l15 = lane & 15;
  int wm = wave & 1, wn = wave >> 1;  // wave-rows of 32, wave-cols of 64
  const float CS = 0.18033688011112042f;  // 0.125 * log2(e), folded into Q
  f32x4 acc[2][4] = {};
  for (int k0 = 0; k0 < 512; k0 += 32) {
    __syncthreads();
    {
      int row = tid >> 2, cc = tid & 3;
      __builtin_amdgcn_global_load_lds(GPTR(A + (size_t)(m0 + row) * 512 + k0 + cc * 8),
                                       LPTR(As + tid * 8), 16, 0, 0);
    }
#pragma unroll
    for (int c = 0; c < 2; c++) {
      int q = tid + c * 256;
      int row = q >> 2, cc = q & 3;
      __builtin_amdgcn_global_load_lds(GPTR(Bw + (size_t)(o0 + row) * 512 + k0 + cc * 8),
                                       LPTR(Bs + q * 8), 16, 0, 0);
    }
    __syncthreads();
    short8 af[2], bf[4];
#pragma unroll
    for (int i = 0; i < 2; i++) af[i] = *(const short8*)(As + (wm * 32 + i * 16 + l15) * 32 + quad * 8);
#pragma unroll
    for (int j = 0; j < 4; j++) bf[j] = *(const short8*)(Bs + (wn * 64 + j * 16 + l15) * 32 + quad * 8);
#pragma unroll
    for (int i = 0; i < 2; i++)
#pragma unroll
      for (int j = 0; j < 4; j++)
        acc[i][j] = __builtin_amdgcn_mfma_f32_16x16x32_bf16(af[i], bf[j], acc[i][j], 0, 0, 0);
  }
#pragma unroll
  for (int i = 0; i < 2; i++) {
#pragma unroll
    for (int j = 0; j < 4; j++) {
      int colo = o0 + wn * 64 + j * 16 + l15;
      int part = colo >> 9, rr = colo & 511, h = rr >> 6, d = rr & 63;
      int mbase = m0 + wm * 32 + i * 16 + quad * 4;
      int b = (mbase >= 2304) ? 1 : 0;
      int n = mbase - b * 2304;
      if (part == 0) {
#pragma unroll
        for (int reg = 0; reg < 4; reg++)
          Qb[((size_t)(b * 8 + h) * 2304 + n + reg) * 64 + d] = f2bf(acc[i][j][reg] * CS);
      } else if (part == 1) {
#pragma unroll
        for (int reg = 0; reg < 4; reg++)
          Kb[((size_t)(b * 8 + h) * 2308 + 4 + n + reg) * 64 + d] = f2bf(acc[i][j][reg]);
      } else {
        unsigned short bv[4];
#pragma unroll
        for (int reg = 0; reg < 4; reg++) bv[reg] = f2bf(acc[i][j][reg]);
        unsigned long long pk = (unsigned long long)bv[0] | ((unsigned long long)bv[1] << 16) |
                                ((unsigned long long)bv[2] << 32) | ((unsigned long long)bv[3] << 48);
        *(unsigned long long*)(Vt + ((size_t)(b * 8 + h) * 64 + d) * 2368 + 4 + n) = pk;
      }
    }
  }
}

// ---------------- flash attention, transposed-S, BARRIER-FREE: K/V read direct from global ----------------
// K tile (8KB) and V tile (8KB) are identical across the block's 4 waves -> L1-resident after
// wave 0. No LDS, no __syncthreads: compiler pipelines kt+1 loads under kt MFMAs via vmcnt.
__global__ __launch_bounds__(256) void attn_kernel(
    const unsigned short* __restrict__ Qb, const unsigned short* __restrict__ Kb,
    const unsigned short* __restrict__ Vt,
    unsigned short* __restrict__ Opart, float* __restrict__ Lbuf) {
  int qt = blockIdx.x, bh = blockIdx.y, sp = blockIdx.z;
  int m0 = qt * 128;
  int kt0 = sp * 10, kt1 = (kt0 + 10 < 37) ? kt0 + 10 : 37;
  const unsigned short* Qh = Qb + (size_t)bh * 2304 * 64;
  const unsigned short* Kh = Kb + (size_t)bh * 2308 * 64;
  const unsigned short* VtH = Vt + (size_t)bh * 64 * 2368;
  int tid = threadIdx.x, lane = tid & 63, wave = tid >> 6;
  int quad = lane >> 4, l15 = lane & 15;

  short8 qf[2][2];  // [im][s] — B-operand of St MFMA
#pragma unroll
  for (int i = 0; i < 2; i++)
#pragma unroll
    for (int s = 0; s < 2; s++)
      qf[i][s] = *(const short8*)(Qh + (size_t)(m0 + wave * 32 + i * 16 + l15) * 64 + s * 32 + quad * 8);

  f32x4 oacc[2][4] = {};   // [im][jo]: rows quad*4+r = m_local, cols l15 = d_local
  float lsumT[2] = {};     // per-lane partial row-sum (lane owns m = l15)

  for (int kt = kt0; kt < kt1; kt++) {
    short4b pt[4][2];  // packed P A-frags, [jn][im]
#pragma unroll
    for (int jn = 0; jn < 4; jn++) {
      f32x4 st[2] = {};
#pragma unroll
      for (int s = 0; s < 2; s++) {
        // K fragment straight from global: row = key, coalesced b128; L1-shared across waves.
        // Tail tile reads past row 2308 -> garbage keys, masked to p=0 below.
        short8 kf = *(const short8*)(Kh + (size_t)(kt * 64 + jn * 16 + l15) * 64 + s * 32 + quad * 8);
#pragma unroll
        for (int im = 0; im < 2; im++)
          st[im] = __builtin_amdgcn_mfma_f32_16x16x32_bf16(kf, qf[im][s], st[im], 0, 0, 0);
      }
#pragma unroll
      for (int im = 0; im < 2; im++) {
#pragma unroll
        for (int r = 0; r < 4; r++) {
          float p = fexp2(st[im][r]);  // CS pre-folded into Q
          if (kt == 36 && (jn * 16 + quad * 4 + r) >= 4) p = 0.f;  // keys >= 2308
          lsumT[im] += p;
          pt[jn][im][r] = bftrunc(p);
        }
      }
    }
    // O += P·V : A = pt (m=lane&15, k=n=quad*4+j), B = Vt rows (d=lane&15), b64 global, L1-hit
#pragma unroll
    for (int jn = 0; jn < 4; jn++) {
#pragma unroll
      for (int jo = 0; jo < 4; jo++) {
        short4b vf = *(const short4b*)(VtH + (size_t)(jo * 16 + l15) * 2368 + kt * 64 + jn * 16 + quad * 4);
#pragma unroll
        for (int im = 0; im < 2; im++)
          oacc[im][jo] = __builtin_amdgcn_mfma_f32_16x16x16bf16_1k(pt[jn][im], vf, oacc[im][jo], 0, 0, 0);
      }
    }
  }
  // total row sums: quads hold disjoint n-ranges -> reduce across quads (lanes same l15)
  size_t obase = (size_t)(sp * 16 + bh) * 2304;
#pragma unroll
  for (int im = 0; im < 2; im++) {
    float v = lsumT[im];
    v += __shfl_xor(v, 16);
    v += __shfl_xor(v, 32);
    if (quad == 0) Lbuf[obase + m0 + wave * 32 + im * 16 + l15] = v;
  }
#pragma unroll
  for (int im = 0; im < 2; im++) {
#pragma unroll
    for (int r = 0; r < 4; r++) {
      int row = m0 + wave * 32 + im * 16 + quad * 4 + r;
#pragma unroll
      for (int jo = 0; jo < 4; jo++)
        Opart[(obase + row) * 64 + jo * 16 + l15] = f2bf(oacc[im][jo][r]);
    }
  }
}

// ---------------- combine 4 splits -> Ot (vectorized); also zeroes GN2 partials ----------------
__global__ __launch_bounds__(256) void combine_kernel(
    const unsigned short* __restrict__ Opart, const float* __restrict__ Lbuf,
    unsigned short* __restrict__ Ot, float* __restrict__ p2s, float* __restrict__ p2q) {
  int t = threadIdx.x;
  if (blockIdx.x == 0 && t < 128) {  // zero 64+64 GN2 accumulators for gemm_out's atomics
    if (t < 64) p2s[t] = 0.f;
    else        p2q[t - 64] = 0.f;
  }
  int rg = blockIdx.x * 16 + (t >> 4);  // global row index 0..36863
  int d4 = (t & 15) * 4;
  int bh = rg / 2304, row = rg - bh * 2304;
  int b = bh >> 3, h = bh & 7;
  float den = 0.f, num[4] = {};
#pragma unroll
  for (int s = 0; s < 4; s++) {
    size_t ri = ((size_t)(s * 16 + bh) * 2304 + row);
    den += Lbuf[ri];
    uint2 pv = *(const uint2*)(Opart + ri * 64 + d4);
    const unsigned short* pp = (const unsigned short*)&pv;
#pragma unroll
    for (int k = 0; k < 4; k++) num[k] += bf2f(pp[k]);
  }
  float rinv = 1.f / den;
  unsigned short ov[4];
#pragma unroll
  for (int k = 0; k < 4; k++) ov[k] = f2bf(num[k] * rinv);
  *(uint2*)(Ot + ((size_t)(b * 2304 + row)) * 512 + h * 64 + d4) = *(uint2*)ov;
}

// ---------------- GEMM2: 64x128 tiles (288 blocks), fused GN2 stats ----------------
__global__ __launch_bounds__(256) void gemm_out_kernel(
    const unsigned short* __restrict__ A, const unsigned short* __restrict__ Bw,
    const float* __restrict__ bias, float* __restrict__ y,
    float* __restrict__ p2s, float* __restrict__ p2q) {
  __shared__ __attribute__((aligned(16))) unsigned short As[64 * 32];
  __shared__ __attribute__((aligned(16))) unsigned short Bs[128 * 32];
  __shared__ float sgrp[8], qgrp[8];
  int m0 = blockIdx.x * 64, o0 = blockIdx.y * 128;
  int tid = threadIdx.x, lane = tid & 63, wave = tid >> 6;
  int quad = lane >> 4, l15 = lane & 15;
  int wm = wave & 1, wn = wave >> 1;
  if (tid < 8) { sgrp[tid] = 0.f; qgrp[tid] = 0.f; }
  f32x4 acc[2][4] = {};
  for (int k0 = 0; k0 < 512; k0 += 32) {
    __syncthreads();
    {
      int row = tid >> 2, cc = tid & 3;
      __builtin_amdgcn_global_load_lds(GPTR(A + (size_t)(m0 + row) * 512 + k0 + cc * 8),
                                       LPTR(As + tid * 8), 16, 0, 0);
    }
#pragma unroll
    for (int c = 0; c < 2; c++) {
      int q = tid + c * 256;
      int row = q >> 2, cc = q & 3;
      __builtin_amdgcn_global_load_lds(GPTR(Bw + (size_t)(o0 + row) * 512 + k0 + cc * 8),
                                       LPTR(Bs + q * 8), 16, 0, 0);
    }
    __syncthreads();
    short8 af[2], bf[4];
#pragma unroll
    for (int i = 0; i < 2; i++) af[i] = *(const short8*)(As + (wm * 32 + i * 16 + l15) * 32 + quad * 8);
#pragma unroll
    for (int j = 0; j < 4; j++) bf[j] = *(const short8*)(Bs + (wn * 64 + j * 16 + l15) * 32 + quad * 8);
#pragma unroll
    for (int i = 0; i < 2; i++)
#pragma unroll
      for (int j = 0; j < 4; j++)
        acc[i][j] = __builtin_amdgcn_mfma_f32_16x16x32_bf16(af[i], bf[j], acc[i][j], 0, 0, 0);
  }
  float ss[4] = {}, qq[4] = {};
#pragma unroll
  for (int i = 0; i < 2; i++) {
#pragma unroll
    for (int j = 0; j < 4; j++) {
      int colo = o0 + wn * 64 + j * 16 + l15;
      float bb = bias[colo];
#pragma unroll
      for (int reg = 0; reg < 4; reg++) {
        int m = m0 + wm * 32 + i * 16 + quad * 4 + reg;
        float v = acc[i][j][reg] + bb;
        y[(size_t)m * 512 + colo] = v;
        ss[j] += v;
        qq[j] += v * v;
      }
    }
  }
#pragma unroll
  for (int j = 0; j < 4; j++) {
#pragma unroll
    for (int o = 1; o < 64; o <<= 1) { ss[j] += __shfl_xor(ss[j], o); qq[j] += __shfl_xor(qq[j], o); }
  }
  if (lane == 0) {
#pragma unroll
    for (int j = 0; j < 4; j++) {
      atomicAdd(&sgrp[wn * 4 + j], ss[j]);
      atomicAdd(&qgrp[wn * 4 + j], qq[j]);
    }
  }
  __syncthreads();
  if (tid < 8) {
    int b = (m0 >= 2304) ? 1 : 0;
    int g = b * 32 + (o0 >> 4) + tid;
    atomicAdd(&p2s[g], sgrp[tid]);
    atomicAdd(&p2q[g], qgrp[tid]);
  }
}

// ---------------- GN2 normalize + transpose to (B,C,N) ----------------
__global__ __launch_bounds__(256) void gn2_final_kernel(const float* __restrict__ y,
    const float* __restrict__ gw, const float* __restrict__ gb,
    const float* __restrict__ p2s, const float* __restrict__ p2q,
    float* __restrict__ out) {
  __shared__ float tile[32][33];
  int n0 = blockIdx.x * 32, c0 = blockIdx.y * 32, b = blockIdx.z;
  int g0 = c0 >> 4;
  float mu2[2], rs2[2];
#pragma unroll
  for (int gg = 0; gg < 2; gg++) {
    float s = p2s[b * 32 + g0 + gg], q = p2q[b * 32 + g0 + gg];
    float mu = s / 36864.f;
    float var = q / 36864.f - mu * mu;
    mu2[gg] = mu;
    rs2[gg] = rsqrtf(var + 1e-5f);
  }
  int tx = threadIdx.x & 31, ty = threadIdx.x >> 5;
#pragma unroll
  for (int r = 0; r < 4; r++) {
    int n = n0 + ty + r * 8;
    tile[ty + r * 8][tx] = y[((size_t)(b * 2304 + n)) * 512 + c0 + tx];
  }
  __syncthreads();
#pragma unroll
  for (int r = 0; r < 4; r++) {
    int c = c0 + ty + r * 8;
    int gg = (ty + r * 8) >> 4;
    float v = tile[tx][ty + r * 8];
    out[((size_t)(b * 512 + c)) * 2304 + n0 + tx] = (v - mu2[gg]) * rs2[gg] * gw[c] + gb[c];
  }
}

extern "C" void kernel_launch(void* const* d_in, const int* in_sizes, int n_in,
                              void* d_out, int out_size, void* d_ws, size_t ws_size,
                              hipStream_t stream) {
  const float* x     = (const float*)d_in[0];
  const float* gn1w  = (const float*)d_in[1];
  const float* gn1b  = (const float*)d_in[2];
  const float* wqkv  = (const float*)d_in[3];
  const float* memkv = (const float*)d_in[4];
  const float* wout  = (const float*)d_in[5];
  const float* bout  = (const float*)d_in[6];
  const float* gn2w  = (const float*)d_in[7];
  const float* gn2b  = (const float*)d_in[8];
  float* out = (float*)d_out;

  char* ws = (char*)d_ws;
  float2* part1        = (float2*)(ws + 0);                 //   4,096
  float* p2s           = (float*)(ws + 4096);               //     256
  float* p2q           = (float*)(ws + 4352);               //     256
  unsigned short* wqB  = (unsigned short*)(ws + 69632);     // 1,572,864
  unsigned short* woB  = (unsigned short*)(ws + 1642496);   //   524,288
  unsigned short* tB   = (unsigned short*)(ws + 2166784);   // 4,718,592
  unsigned short* Qb   = (unsigned short*)(ws + 6885376);   // 4,718,592
  unsigned short* Kb   = (unsigned short*)(ws + 11603968);  // 4,726,784
  unsigned short* Ot   = (unsigned short*)(ws + 21057536);  // 4,718,592
  float* y             = (float*)(ws + 25776128);           // 9,437,184
  unsigned short* Vt   = (unsigned short*)(ws + 35213312);  // 4,849,664
  unsigned short* Opart= (unsigned short*)(ws + 40062976);  // 18,874,368
  float* Lbuf          = (float*)(ws + 58937344);           //   589,824
  // total workspace use: 59,527,168 bytes

  gn1_stats_kernel<<<512, 256, 0, stream>>>(x, part1);
  tnorm_prep_kernel<<<6432, 256, 0, stream>>>(x, gn1w, gn1b, part1, tB,
                                              wqkv, wout, memkv, wqB, woB, Kb, Vt);
  gemm_qkv_kernel<<<dim3(72, 12), 256, 0, stream>>>(tB, wqB, Qb, Kb, Vt);
  attn_kernel<<<dim3(18, 16, 4), 256, 0, stream>>>(Qb, Kb, Vt, Opart, Lbuf);
  combine_kernel<<<2304, 256, 0, stream>>>(Opart, Lbuf, Ot, p2s, p2q);
  gemm_out_kernel<<<dim3(72, 4), 256, 0, stream>>>(Ot, woB, bout, y, p2s, p2q);
  gn2_final_kernel<<<dim3(72, 16, 2), 256, 0, stream>>>(y, gn2w, gn2b, p2s, p2q, out);
}

// Round 14
// 165.443 us; speedup vs baseline: 1.5323x; 1.5323x over previous
//
#include <hip/hip_runtime.h>
#include <hip/hip_bf16.h>

typedef short short8 __attribute__((ext_vector_type(8)));
typedef short short4b __attribute__((ext_vector_type(4)));
typedef float f32x4 __attribute__((ext_vector_type(4)));

#define GPTR(x) ((const __attribute__((address_space(1))) void*)(x))
#define LPTR(x) ((__attribute__((address_space(3))) void*)(x))

static __device__ __forceinline__ unsigned short f2bf(float f) {
  __hip_bfloat16 h = __float2bfloat16(f);
  return __builtin_bit_cast(unsigned short, h);
}
static __device__ __forceinline__ float bf2f(unsigned short u) {
  unsigned int v = ((unsigned int)u) << 16;
  return __builtin_bit_cast(float, v);
}
// raw v_exp_f32 (no libm guards)
static __device__ __forceinline__ float fexp2(float x) {
#if __has_builtin(__builtin_amdgcn_exp2f)
  return __builtin_amdgcn_exp2f(x);
#else
  return exp2f(x);
#endif
}
// truncating f32->bf16 (1 shift vs ~5-op RNE); P numerator only, ~-0.2% bias cancels in ratio
static __device__ __forceinline__ short bftrunc(float f) {
  return (short)(__builtin_bit_cast(unsigned int, f) >> 16);
}

// ---------------- block reduction helper ----------------
static __device__ __forceinline__ void block_reduce2(float& s, float& q) {
#pragma unroll
  for (int o = 32; o > 0; o >>= 1) { s += __shfl_down(s, o); q += __shfl_down(q, o); }
  __shared__ float rs[4], rq[4];
  int tid = threadIdx.x;
  if ((tid & 63) == 0) { rs[tid >> 6] = s; rq[tid >> 6] = q; }
  __syncthreads();
  if (tid == 0) {
    s = rs[0] + rs[1] + rs[2] + rs[3];
    q = rq[0] + rq[1] + rq[2] + rq[3];
  }
}

// ---------------- GN1 stats stage 1: 512 blocks ----------------
__global__ __launch_bounds__(256) void gn1_stats_kernel(const float* __restrict__ x,
                                                        float2* __restrict__ part1) {
  int bgc = blockIdx.x;  // (b*32+g)*8 + chunk
  const float4* base = (const float4*)x + (size_t)bgc * 1152;
  float s = 0.f, q = 0.f;
  for (int i = threadIdx.x; i < 1152; i += 256) {
    float4 v = base[i];
    s += v.x + v.y + v.z + v.w;
    q += v.x * v.x + v.y * v.y + v.z * v.z + v.w * v.w;
  }
  block_reduce2(s, q);
  if (threadIdx.x == 0) part1[bgc] = make_float2(s, q);
}

// ---------------- fused: tnorm (blocks 0..2303) + weight prep / mem-KV (blocks 2304..6431) ----------------
__global__ __launch_bounds__(256) void tnorm_prep_kernel(const float* __restrict__ x,
    const float* __restrict__ gw, const float* __restrict__ gb,
    const float2* __restrict__ part1, unsigned short* __restrict__ t,
    const float* __restrict__ wqkv, const float* __restrict__ wout,
    const float* __restrict__ memkv,
    unsigned short* __restrict__ wq, unsigned short* __restrict__ wo,
    unsigned short* __restrict__ Kb, unsigned short* __restrict__ Vt) {
  __shared__ float tile[32][33];
  int blk = blockIdx.x;
  if (blk < 2304) {
    int n0 = (blk % 72) * 32, c0 = ((blk / 72) & 15) * 32, b = blk / 1152;
    int g0 = c0 >> 4;
    float mu2[2], rs2[2];
#pragma unroll
    for (int gg = 0; gg < 2; gg++) {
      float s = 0.f, q = 0.f;
      const float2* p = part1 + (size_t)(b * 32 + g0 + gg) * 8;
#pragma unroll
      for (int k = 0; k < 8; k++) { float2 v = p[k]; s += v.x; q += v.y; }
      float mu = s / 36864.f;
      float var = q / 36864.f - mu * mu;
      mu2[gg] = mu;
      rs2[gg] = rsqrtf(var + 1e-5f);
    }
    int tx = threadIdx.x & 31, ty = threadIdx.x >> 5;
#pragma unroll
    for (int r = 0; r < 4; r++) {
      int c = c0 + ty + r * 8;
      tile[ty + r * 8][tx] = x[((size_t)(b * 512 + c)) * 2304 + n0 + tx];
    }
    __syncthreads();
    int gg = tx >> 4;
#pragma unroll
    for (int r = 0; r < 4; r++) {
      int n = n0 + ty + r * 8;
      int c = c0 + tx;
      float v = tile[tx][ty + r * 8];
      t[((size_t)(b * 2304 + n)) * 512 + c] = f2bf((v - mu2[gg]) * rs2[gg] * gw[c] + gb[c]);
    }
  } else {
    int i = (blk - 2304) * 256 + threadIdx.x;
    if (i < 786432) {
      wq[i] = f2bf(wqkv[i]);
    } else if (i < 1048576) {
      int j = i - 786432;
      wo[j] = f2bf(wout[j]);
    } else if (i < 1056768) {
      int tt = i - 1048576;  // (((s*2+b)*8+h)*4+j)*64+d
      int d = tt & 63, j = (tt >> 6) & 3, h = (tt >> 8) & 7, b = (tt >> 11) & 1, s = tt >> 12;
      unsigned short bv = f2bf(memkv[((s * 8 + h) * 64 + d) * 4 + j]);
      if (s == 0) Kb[((size_t)(b * 8 + h) * 2308 + j) * 64 + d] = bv;
      else        Vt[((size_t)(b * 8 + h) * 64 + d) * 2368 + j] = bv;
    }
  }
}

// ---------------- GEMM1: 64x128 tiles (864 blocks); Q pre-scaled by CS; V direct-transposed ----------------
__global__ __launch_bounds__(256) void gemm_qkv_kernel(
    const unsigned short* __restrict__ A, const unsigned short* __restrict__ Bw,
    unsigned short* __restrict__ Qb, unsigned short* __restrict__ Kb,
    unsigned short* __restrict__ Vt) {
  __shared__ __attribute__((aligned(16))) unsigned short As[64 * 32];
  __shared__ __attribute__((aligned(16))) unsigned short Bs[128 * 32];
  int m0 = blockIdx.x * 64, o0 = blockIdx.y * 128;
  int tid = threadIdx.x, lane = tid & 63, wave = tid >> 6;
  int quad = lane >> 4, l15 = lane & 15;
  int wm = wave & 1, wn = wave >> 1;  // wave-rows of 32, wave-cols of 64
  const float CS = 0.18033688011112042f;  // 0.125 * log2(e), folded into Q
  f32x4 acc[2][4] = {};
  for (int k0 = 0; k0 < 512; k0 += 32) {
    __syncthreads();
    {
      int row = tid >> 2, cc = tid & 3;
      __builtin_amdgcn_global_load_lds(GPTR(A + (size_t)(m0 + row) * 512 + k0 + cc * 8),
                                       LPTR(As + tid * 8), 16, 0, 0);
    }
#pragma unroll
    for (int c = 0; c < 2; c++) {
      int q = tid + c * 256;
      int row = q >> 2, cc = q & 3;
      __builtin_amdgcn_global_load_lds(GPTR(Bw + (size_t)(o0 + row) * 512 + k0 + cc * 8),
                                       LPTR(Bs + q * 8), 16, 0, 0);
    }
    __syncthreads();
    short8 af[2], bf[4];
#pragma unroll
    for (int i = 0; i < 2; i++) af[i] = *(const short8*)(As + (wm * 32 + i * 16 + l15) * 32 + quad * 8);
#pragma unroll
    for (int j = 0; j < 4; j++) bf[j] = *(const short8*)(Bs + (wn * 64 + j * 16 + l15) * 32 + quad * 8);
#pragma unroll
    for (int i = 0; i < 2; i++)
#pragma unroll
      for (int j = 0; j < 4; j++)
        acc[i][j] = __builtin_amdgcn_mfma_f32_16x16x32_bf16(af[i], bf[j], acc[i][j], 0, 0, 0);
  }
#pragma unroll
  for (int i = 0; i < 2; i++) {
#pragma unroll
    for (int j = 0; j < 4; j++) {
      int colo = o0 + wn * 64 + j * 16 + l15;
      int part = colo >> 9, rr = colo & 511, h = rr >> 6, d = rr & 63;
      int mbase = m0 + wm * 32 + i * 16 + quad * 4;
      int b = (mbase >= 2304) ? 1 : 0;
      int n = mbase - b * 2304;
      if (part == 0) {
#pragma unroll
        for (int reg = 0; reg < 4; reg++)
          Qb[((size_t)(b * 8 + h) * 2304 + n + reg) * 64 + d] = f2bf(acc[i][j][reg] * CS);
      } else if (part == 1) {
#pragma unroll
        for (int reg = 0; reg < 4; reg++)
          Kb[((size_t)(b * 8 + h) * 2308 + 4 + n + reg) * 64 + d] = f2bf(acc[i][j][reg]);
      } else {
        unsigned short bv[4];
#pragma unroll
        for (int reg = 0; reg < 4; reg++) bv[reg] = f2bf(acc[i][j][reg]);
        unsigned long long pk = (unsigned long long)bv[0] | ((unsigned long long)bv[1] << 16) |
                                ((unsigned long long)bv[2] << 32) | ((unsigned long long)bv[3] << 48);
        *(unsigned long long*)(Vt + ((size_t)(b * 8 + h) * 64 + d) * 2368 + 4 + n) = pk;
      }
    }
  }
}

// ---------------- flash attention, transposed-S: P stays in registers (exact R12 version) ----------------
__global__ __launch_bounds__(256) void attn_kernel(
    const unsigned short* __restrict__ Qb, const unsigned short* __restrict__ Kb,
    const unsigned short* __restrict__ Vt,
    unsigned short* __restrict__ Opart, float* __restrict__ Lbuf) {
  __shared__ __attribute__((aligned(16))) unsigned short Ks[64 * 72];   // [key][d] pad 72
  __shared__ __attribute__((aligned(16))) unsigned short Vts[64 * 68];  // [d][key] pad 68
  int qt = blockIdx.x, bh = blockIdx.y, sp = blockIdx.z;
  int m0 = qt * 128;
  int kt0 = sp * 10, kt1 = (kt0 + 10 < 37) ? kt0 + 10 : 37;
  const unsigned short* Qh = Qb + (size_t)bh * 2304 * 64;
  const unsigned short* Kh = Kb + (size_t)bh * 2308 * 64;
  const unsigned short* VtH = Vt + (size_t)bh * 64 * 2368;
  int tid = threadIdx.x, lane = tid & 63, wave = tid >> 6;
  int quad = lane >> 4, l15 = lane & 15;

  short8 qf[2][2];  // [im][s] — B-operand of St MFMA
#pragma unroll
  for (int i = 0; i < 2; i++)
#pragma unroll
    for (int s = 0; s < 2; s++)
      qf[i][s] = *(const short8*)(Qh + (size_t)(m0 + wave * 32 + i * 16 + l15) * 64 + s * 32 + quad * 8);

  f32x4 oacc[2][4] = {};   // [im][jo]: rows quad*4+r = m_local, cols l15 = d_local
  float lsumT[2] = {};     // per-lane partial row-sum (lane owns m = l15)

  for (int kt = kt0; kt < kt1; kt++) {
    __syncthreads();  // prior tile's Ks/Vts reads done
#pragma unroll
    for (int c = 0; c < 2; c++) {
      int q = tid + c * 256;
      int krow = q >> 3, c8 = q & 7;
      int gk = kt * 64 + krow;
      uint4 kv = make_uint4(0, 0, 0, 0);
      if (gk < 2308) kv = *(const uint4*)(Kh + (size_t)gk * 64 + c8 * 8);
      *(uint4*)(Ks + krow * 72 + c8 * 8) = kv;
      uint4 vv = *(const uint4*)(VtH + (size_t)krow * 2368 + kt * 64 + c8 * 8);  // krow is d here
      *(uint4*)(Vts + krow * 68 + c8 * 8) = vv;
    }
    __syncthreads();  // staging visible
    short4b pt[4][2];  // packed P A-frags, [jn][im]
#pragma unroll
    for (int jn = 0; jn < 4; jn++) {
      f32x4 st[2] = {};
#pragma unroll
      for (int s = 0; s < 2; s++) {
        short8 kf = *(const short8*)(Ks + (jn * 16 + l15) * 72 + s * 32 + quad * 8);
#pragma unroll
        for (int im = 0; im < 2; im++)
          st[im] = __builtin_amdgcn_mfma_f32_16x16x32_bf16(kf, qf[im][s], st[im], 0, 0, 0);
      }
#pragma unroll
      for (int im = 0; im < 2; im++) {
#pragma unroll
        for (int r = 0; r < 4; r++) {
          float p = fexp2(st[im][r]);  // CS pre-folded into Q
          if (kt == 36 && (jn * 16 + quad * 4 + r) >= 4) p = 0.f;  // keys >= 2308
          lsumT[im] += p;
          pt[jn][im][r] = bftrunc(p);
        }
      }
    }
    // O += P·V : A = pt (m=lane&15, k=n=quad*4+j), B = Vts rows (d=lane&15, k=n=quad*4+j)
#pragma unroll
    for (int jn = 0; jn < 4; jn++) {
#pragma unroll
      for (int jo = 0; jo < 4; jo++) {
        short4b vf = *(const short4b*)(Vts + (jo * 16 + l15) * 68 + jn * 16 + quad * 4);
#pragma unroll
        for (int im = 0; im < 2; im++)
          oacc[im][jo] = __builtin_amdgcn_mfma_f32_16x16x16bf16_1k(pt[jn][im], vf, oacc[im][jo], 0, 0, 0);
      }
    }
  }
  // total row sums: quads hold disjoint n-ranges -> reduce across quads (lanes same l15)
  size_t obase = (size_t)(sp * 16 + bh) * 2304;
#pragma unroll
  for (int im = 0; im < 2; im++) {
    float v = lsumT[im];
    v += __shfl_xor(v, 16);
    v += __shfl_xor(v, 32);
    if (quad == 0) Lbuf[obase + m0 + wave * 32 + im * 16 + l15] = v;
  }
#pragma unroll
  for (int im = 0; im < 2; im++) {
#pragma unroll
    for (int r = 0; r < 4; r++) {
      int row = m0 + wave * 32 + im * 16 + quad * 4 + r;
#pragma unroll
      for (int jo = 0; jo < 4; jo++)
        Opart[(obase + row) * 64 + jo * 16 + l15] = f2bf(oacc[im][jo][r]);
    }
  }
}

// ---------------- GEMM2: 64x128 tiles (288 blocks), fused split-combine A-staging + GN2 stats ----------------
// A[m, col] = (sum_s Opart_s[m, head(col), d]) / (sum_s L_s[m, head(col)]) computed during staging;
// deletes the standalone combine kernel and the Ot round-trip.
__global__ __launch_bounds__(256) void gemm_out_kernel(
    const unsigned short* __restrict__ Opart, const float* __restrict__ Lbuf,
    const unsigned short* __restrict__ Bw,
    const float* __restrict__ bias, float* __restrict__ y,
    float* __restrict__ p2s, float* __restrict__ p2q) {
  __shared__ __attribute__((aligned(16))) unsigned short As[64 * 32];
  __shared__ __attribute__((aligned(16))) unsigned short Bs[128 * 32];
  __shared__ float sgrp[8], qgrp[8];
  int m0 = blockIdx.x * 64, o0 = blockIdx.y * 128;
  int tid = threadIdx.x, lane = tid & 63, wave = tid >> 6;
  int quad = lane >> 4, l15 = lane & 15;
  int wm = wave & 1, wn = wave >> 1;
  if (tid < 8) { sgrp[tid] = 0.f; qgrp[tid] = 0.f; }
  int bB = (m0 >= 2304) ? 1 : 0;                 // batch uniform per block (m0 multiple of 64)
  int arow = tid >> 2, acc8 = tid & 3;
  int an = m0 + arow - bB * 2304;                // token row for A staging
  f32x4 acc[2][4] = {};
  for (int k0 = 0; k0 < 512; k0 += 32) {
    __syncthreads();
    {  // fused combine: build A fragment (8 bf16) in registers, ds_write_b128
      int col = k0 + acc8 * 8;
      int bh = bB * 8 + (col >> 6), d0 = col & 63;
      float den = 0.f, num[8] = {};
#pragma unroll
      for (int s = 0; s < 4; s++) {
        size_t ri = ((size_t)(s * 16 + bh) * 2304 + an);
        den += Lbuf[ri];
        uint4 pv = *(const uint4*)(Opart + ri * 64 + d0);
        const unsigned short* pp = (const unsigned short*)&pv;
#pragma unroll
        for (int k = 0; k < 8; k++) num[k] += bf2f(pp[k]);
      }
      float rinv = 1.f / den;
      unsigned short av[8];
#pragma unroll
      for (int k = 0; k < 8; k++) av[k] = f2bf(num[k] * rinv);
      *(uint4*)(As + tid * 8) = *(const uint4*)av;
    }
#pragma unroll
    for (int c = 0; c < 2; c++) {
      int q = tid + c * 256;
      int row = q >> 2, cc = q & 3;
      __builtin_amdgcn_global_load_lds(GPTR(Bw + (size_t)(o0 + row) * 512 + k0 + cc * 8),
                                       LPTR(Bs + q * 8), 16, 0, 0);
    }
    __syncthreads();
    short8 af[2], bf[4];
#pragma unroll
    for (int i = 0; i < 2; i++) af[i] = *(const short8*)(As + (wm * 32 + i * 16 + l15) * 32 + quad * 8);
#pragma unroll
    for (int j = 0; j < 4; j++) bf[j] = *(const short8*)(Bs + (wn * 64 + j * 16 + l15) * 32 + quad * 8);
#pragma unroll
    for (int i = 0; i < 2; i++)
#pragma unroll
      for (int j = 0; j < 4; j++)
        acc[i][j] = __builtin_amdgcn_mfma_f32_16x16x32_bf16(af[i], bf[j], acc[i][j], 0, 0, 0);
  }
  float ss[4] = {}, qq[4] = {};
#pragma unroll
  for (int i = 0; i < 2; i++) {
#pragma unroll
    for (int j = 0; j < 4; j++) {
      int colo = o0 + wn * 64 + j * 16 + l15;
      float bb = bias[colo];
#pragma unroll
      for (int reg = 0; reg < 4; reg++) {
        int m = m0 + wm * 32 + i * 16 + quad * 4 + reg;
        float v = acc[i][j][reg] + bb;
        y[(size_t)m * 512 + colo] = v;
        ss[j] += v;
        qq[j] += v * v;
      }
    }
  }
#pragma unroll
  for (int j = 0; j < 4; j++) {
#pragma unroll
    for (int o = 1; o < 64; o <<= 1) { ss[j] += __shfl_xor(ss[j], o); qq[j] += __shfl_xor(qq[j], o); }
  }
  if (lane == 0) {
#pragma unroll
    for (int j = 0; j < 4; j++) {
      atomicAdd(&sgrp[wn * 4 + j], ss[j]);
      atomicAdd(&qgrp[wn * 4 + j], qq[j]);
    }
  }
  __syncthreads();
  if (tid < 8) {
    int g = bB * 32 + (o0 >> 4) + tid;
    atomicAdd(&p2s[g], sgrp[tid]);
    atomicAdd(&p2q[g], qgrp[tid]);
  }
}

// ---------------- GN2 normalize + transpose to (B,C,N) ----------------
__global__ __launch_bounds__(256) void gn2_final_kernel(const float* __restrict__ y,
    const float* __restrict__ gw, const float* __restrict__ gb,
    const float* __restrict__ p2s, const float* __restrict__ p2q,
    float* __restrict__ out) {
  __shared__ float tile[32][33];
  int n0 = blockIdx.x * 32, c0 = blockIdx.y * 32, b = blockIdx.z;
  int g0 = c0 >> 4;
  float mu2[2], rs2[2];
#pragma unroll
  for (int gg = 0; gg < 2; gg++) {
    float s = p2s[b * 32 + g0 + gg], q = p2q[b * 32 + g0 + gg];
    float mu = s / 36864.f;
    float var = q / 36864.f - mu * mu;
    mu2[gg] = mu;
    rs2[gg] = rsqrtf(var + 1e-5f);
  }
  int tx = threadIdx.x & 31, ty = threadIdx.x >> 5;
#pragma unroll
  for (int r = 0; r < 4; r++) {
    int n = n0 + ty + r * 8;
    tile[ty + r * 8][tx] = y[((size_t)(b * 2304 + n)) * 512 + c0 + tx];
  }
  __syncthreads();
#pragma unroll
  for (int r = 0; r < 4; r++) {
    int c = c0 + ty + r * 8;
    int gg = (ty + r * 8) >> 4;
    float v = tile[tx][ty + r * 8];
    out[((size_t)(b * 512 + c)) * 2304 + n0 + tx] = (v - mu2[gg]) * rs2[gg] * gw[c] + gb[c];
  }
}

extern "C" void kernel_launch(void* const* d_in, const int* in_sizes, int n_in,
                              void* d_out, int out_size, void* d_ws, size_t ws_size,
                              hipStream_t stream) {
  const float* x     = (const float*)d_in[0];
  const float* gn1w  = (const float*)d_in[1];
  const float* gn1b  = (const float*)d_in[2];
  const float* wqkv  = (const float*)d_in[3];
  const float* memkv = (const float*)d_in[4];
  const float* wout  = (const float*)d_in[5];
  const float* bout  = (const float*)d_in[6];
  const float* gn2w  = (const float*)d_in[7];
  const float* gn2b  = (const float*)d_in[8];
  float* out = (float*)d_out;

  char* ws = (char*)d_ws;
  float2* part1        = (float2*)(ws + 0);                 //   4,096
  float* p2s           = (float*)(ws + 4096);               //     256
  float* p2q           = (float*)(ws + 4352);               //     256
  unsigned short* wqB  = (unsigned short*)(ws + 69632);     // 1,572,864
  unsigned short* woB  = (unsigned short*)(ws + 1642496);   //   524,288
  unsigned short* tB   = (unsigned short*)(ws + 2166784);   // 4,718,592
  unsigned short* Qb   = (unsigned short*)(ws + 6885376);   // 4,718,592
  unsigned short* Kb   = (unsigned short*)(ws + 11603968);  // 4,726,784
  float* y             = (float*)(ws + 25776128);           // 9,437,184
  unsigned short* Vt   = (unsigned short*)(ws + 35213312);  // 4,849,664
  unsigned short* Opart= (unsigned short*)(ws + 40062976);  // 18,874,368
  float* Lbuf          = (float*)(ws + 58937344);           //   589,824
  // total workspace use: 59,527,168 bytes

  gn1_stats_kernel<<<512, 256, 0, stream>>>(x, part1);
  tnorm_prep_kernel<<<6432, 256, 0, stream>>>(x, gn1w, gn1b, part1, tB,
                                              wqkv, wout, memkv, wqB, woB, Kb, Vt);
  gemm_qkv_kernel<<<dim3(72, 12), 256, 0, stream>>>(tB, wqB, Qb, Kb, Vt);
  hipMemsetAsync(ws + 4096, 0, 512, stream);  // zero p2s/p2q for gemm_out atomics
  attn_kernel<<<dim3(18, 16, 4), 256, 0, stream>>>(Qb, Kb, Vt, Opart, Lbuf);
  gemm_out_kernel<<<dim3(72, 4), 256, 0, stream>>>(Opart, Lbuf, woB, bout, y, p2s, p2q);
  gn2_final_kernel<<<dim3(72, 16, 2), 256, 0, stream>>>(y, gn2w, gn2b, p2s, p2q, out);
}

// Round 15
// 161.537 us; speedup vs baseline: 1.5694x; 1.0242x over previous
//
#include <hip/hip_runtime.h>
#include <hip/hip_bf16.h>

typedef short short8 __attribute__((ext_vector_type(8)));
typedef short short4b __attribute__((ext_vector_type(4)));
typedef float f32x4 __attribute__((ext_vector_type(4)));

#define GPTR(x) ((const __attribute__((address_space(1))) void*)(x))
#define LPTR(x) ((__attribute__((address_space(3))) void*)(x))

static __device__ __forceinline__ unsigned short f2bf(float f) {
  __hip_bfloat16 h = __float2bfloat16(f);
  return __builtin_bit_cast(unsigned short, h);
}
static __device__ __forceinline__ float bf2f(unsigned short u) {
  unsigned int v = ((unsigned int)u) << 16;
  return __builtin_bit_cast(float, v);
}
// raw v_exp_f32 (no libm guards)
static __device__ __forceinline__ float fexp2(float x) {
#if __has_builtin(__builtin_amdgcn_exp2f)
  return __builtin_amdgcn_exp2f(x);
#else
  return exp2f(x);
#endif
}
// truncating f32->bf16 (1 shift vs ~5-op RNE); P numerator only, ~-0.2% bias cancels in ratio
static __device__ __forceinline__ short bftrunc(float f) {
  return (short)(__builtin_bit_cast(unsigned int, f) >> 16);
}

// ---------------- block reduction helper ----------------
static __device__ __forceinline__ void block_reduce2(float& s, float& q) {
#pragma unroll
  for (int o = 32; o > 0; o >>= 1) { s += __shfl_down(s, o); q += __shfl_down(q, o); }
  __shared__ float rs[4], rq[4];
  int tid = threadIdx.x;
  if ((tid & 63) == 0) { rs[tid >> 6] = s; rq[tid >> 6] = q; }
  __syncthreads();
  if (tid == 0) {
    s = rs[0] + rs[1] + rs[2] + rs[3];
    q = rq[0] + rq[1] + rq[2] + rq[3];
  }
}

// ---------------- GN1 stats stage 1: 512 blocks ----------------
__global__ __launch_bounds__(256) void gn1_stats_kernel(const float* __restrict__ x,
                                                        float2* __restrict__ part1) {
  int bgc = blockIdx.x;  // (b*32+g)*8 + chunk
  const float4* base = (const float4*)x + (size_t)bgc * 1152;
  float s = 0.f, q = 0.f;
  for (int i = threadIdx.x; i < 1152; i += 256) {
    float4 v = base[i];
    s += v.x + v.y + v.z + v.w;
    q += v.x * v.x + v.y * v.y + v.z * v.z + v.w * v.w;
  }
  block_reduce2(s, q);
  if (threadIdx.x == 0) part1[bgc] = make_float2(s, q);
}

// ---------------- fused: tnorm (blocks 0..2303) + weight prep / mem-KV (blocks 2304..6431) ----------------
__global__ __launch_bounds__(256) void tnorm_prep_kernel(const float* __restrict__ x,
    const float* __restrict__ gw, const float* __restrict__ gb,
    const float2* __restrict__ part1, unsigned short* __restrict__ t,
    const float* __restrict__ wqkv, const float* __restrict__ wout,
    const float* __restrict__ memkv,
    unsigned short* __restrict__ wq, unsigned short* __restrict__ wo,
    unsigned short* __restrict__ Kb, unsigned short* __restrict__ Vt) {
  __shared__ float tile[32][33];
  int blk = blockIdx.x;
  if (blk < 2304) {
    int n0 = (blk % 72) * 32, c0 = ((blk / 72) & 15) * 32, b = blk / 1152;
    int g0 = c0 >> 4;
    float mu2[2], rs2[2];
#pragma unroll
    for (int gg = 0; gg < 2; gg++) {
      float s = 0.f, q = 0.f;
      const float2* p = part1 + (size_t)(b * 32 + g0 + gg) * 8;
#pragma unroll
      for (int k = 0; k < 8; k++) { float2 v = p[k]; s += v.x; q += v.y; }
      float mu = s / 36864.f;
      float var = q / 36864.f - mu * mu;
      mu2[gg] = mu;
      rs2[gg] = rsqrtf(var + 1e-5f);
    }
    int tx = threadIdx.x & 31, ty = threadIdx.x >> 5;
#pragma unroll
    for (int r = 0; r < 4; r++) {
      int c = c0 + ty + r * 8;
      tile[ty + r * 8][tx] = x[((size_t)(b * 512 + c)) * 2304 + n0 + tx];
    }
    __syncthreads();
    int gg = tx >> 4;
#pragma unroll
    for (int r = 0; r < 4; r++) {
      int n = n0 + ty + r * 8;
      int c = c0 + tx;
      float v = tile[tx][ty + r * 8];
      t[((size_t)(b * 2304 + n)) * 512 + c] = f2bf((v - mu2[gg]) * rs2[gg] * gw[c] + gb[c]);
    }
  } else {
    int i = (blk - 2304) * 256 + threadIdx.x;
    if (i < 786432) {
      wq[i] = f2bf(wqkv[i]);
    } else if (i < 1048576) {
      int j = i - 786432;
      wo[j] = f2bf(wout[j]);
    } else if (i < 1056768) {
      int tt = i - 1048576;  // (((s*2+b)*8+h)*4+j)*64+d
      int d = tt & 63, j = (tt >> 6) & 3, h = (tt >> 8) & 7, b = (tt >> 11) & 1, s = tt >> 12;
      unsigned short bv = f2bf(memkv[((s * 8 + h) * 64 + d) * 4 + j]);
      if (s == 0) Kb[((size_t)(b * 8 + h) * 2308 + j) * 64 + d] = bv;
      else        Vt[((size_t)(b * 8 + h) * 64 + d) * 2368 + j] = bv;
    }
  }
}

// ---------------- GEMM1: 64x128 tiles (864 blocks); Q pre-scaled by CS; V direct-transposed ----------------
__global__ __launch_bounds__(256) void gemm_qkv_kernel(
    const unsigned short* __restrict__ A, const unsigned short* __restrict__ Bw,
    unsigned short* __restrict__ Qb, unsigned short* __restrict__ Kb,
    unsigned short* __restrict__ Vt) {
  __shared__ __attribute__((aligned(16))) unsigned short As[64 * 32];
  __shared__ __attribute__((aligned(16))) unsigned short Bs[128 * 32];
  int m0 = blockIdx.x * 64, o0 = blockIdx.y * 128;
  int tid = threadIdx.x, lane = tid & 63, wave = tid >> 6;
  int quad = lane >> 4, l15 = lane & 15;
  int wm = wave & 1, wn = wave >> 1;  // wave-rows of 32, wave-cols of 64
  const float CS = 0.18033688011112042f;  // 0.125 * log2(e), folded into Q
  f32x4 acc[2][4] = {};
  for (int k0 = 0; k0 < 512; k0 += 32) {
    __syncthreads();
    {
      int row = tid >> 2, cc = tid & 3;
      __builtin_amdgcn_global_load_lds(GPTR(A + (size_t)(m0 + row) * 512 + k0 + cc * 8),
                                       LPTR(As + tid * 8), 16, 0, 0);
    }
#pragma unroll
    for (int c = 0; c < 2; c++) {
      int q = tid + c * 256;
      int row = q >> 2, cc = q & 3;
      __builtin_amdgcn_global_load_lds(GPTR(Bw + (size_t)(o0 + row) * 512 + k0 + cc * 8),
                                       LPTR(Bs + q * 8), 16, 0, 0);
    }
    __syncthreads();
    short8 af[2], bf[4];
#pragma unroll
    for (int i = 0; i < 2; i++) af[i] = *(const short8*)(As + (wm * 32 + i * 16 + l15) * 32 + quad * 8);
#pragma unroll
    for (int j = 0; j < 4; j++) bf[j] = *(const short8*)(Bs + (wn * 64 + j * 16 + l15) * 32 + quad * 8);
#pragma unroll
    for (int i = 0; i < 2; i++)
#pragma unroll
      for (int j = 0; j < 4; j++)
        acc[i][j] = __builtin_amdgcn_mfma_f32_16x16x32_bf16(af[i], bf[j], acc[i][j], 0, 0, 0);
  }
#pragma unroll
  for (int i = 0; i < 2; i++) {
#pragma unroll
    for (int j = 0; j < 4; j++) {
      int colo = o0 + wn * 64 + j * 16 + l15;
      int part = colo >> 9, rr = colo & 511, h = rr >> 6, d = rr & 63;
      int mbase = m0 + wm * 32 + i * 16 + quad * 4;
      int b = (mbase >= 2304) ? 1 : 0;
      int n = mbase - b * 2304;
      if (part == 0) {
#pragma unroll
        for (int reg = 0; reg < 4; reg++)
          Qb[((size_t)(b * 8 + h) * 2304 + n + reg) * 64 + d] = f2bf(acc[i][j][reg] * CS);
      } else if (part == 1) {
#pragma unroll
        for (int reg = 0; reg < 4; reg++)
          Kb[((size_t)(b * 8 + h) * 2308 + 4 + n + reg) * 64 + d] = f2bf(acc[i][j][reg]);
      } else {
        unsigned short bv[4];
#pragma unroll
        for (int reg = 0; reg < 4; reg++) bv[reg] = f2bf(acc[i][j][reg]);
        unsigned long long pk = (unsigned long long)bv[0] | ((unsigned long long)bv[1] << 16) |
                                ((unsigned long long)bv[2] << 32) | ((unsigned long long)bv[3] << 48);
        *(unsigned long long*)(Vt + ((size_t)(b * 8 + h) * 64 + d) * 2368 + 4 + n) = pk;
      }
    }
  }
}

// ---------------- flash attention, transposed-S, BM=64 (grid 36x16x4 = 2304 blocks, 9/CU) ----------------
// R12 structure with halved Q-tile: each wave owns 16 query rows; P stays in registers.
__global__ __launch_bounds__(256) void attn_kernel(
    const unsigned short* __restrict__ Qb, const unsigned short* __restrict__ Kb,
    const unsigned short* __restrict__ Vt,
    unsigned short* __restrict__ Opart, float* __restrict__ Lbuf) {
  __shared__ __attribute__((aligned(16))) unsigned short Ks[64 * 72];   // [key][d] pad 72
  __shared__ __attribute__((aligned(16))) unsigned short Vts[64 * 68];  // [d][key] pad 68
  int qt = blockIdx.x, bh = blockIdx.y, sp = blockIdx.z;
  int m0 = qt * 64;
  int kt0 = sp * 10, kt1 = (kt0 + 10 < 37) ? kt0 + 10 : 37;
  const unsigned short* Qh = Qb + (size_t)bh * 2304 * 64;
  const unsigned short* Kh = Kb + (size_t)bh * 2308 * 64;
  const unsigned short* VtH = Vt + (size_t)bh * 64 * 2368;
  int tid = threadIdx.x, lane = tid & 63, wave = tid >> 6;
  int quad = lane >> 4, l15 = lane & 15;

  short8 qf[2];  // [s] — B-operand of St MFMA; wave owns rows m0+wave*16 .. +15
#pragma unroll
  for (int s = 0; s < 2; s++)
    qf[s] = *(const short8*)(Qh + (size_t)(m0 + wave * 16 + l15) * 64 + s * 32 + quad * 8);

  f32x4 oacc[4] = {};  // [jo]: rows quad*4+r = m_local, cols l15 = d_local
  float lsumT = 0.f;   // per-lane partial row-sum (lane owns m = l15)

  for (int kt = kt0; kt < kt1; kt++) {
    __syncthreads();  // prior tile's Ks/Vts reads done
#pragma unroll
    for (int c = 0; c < 2; c++) {
      int q = tid + c * 256;
      int krow = q >> 3, c8 = q & 7;
      int gk = kt * 64 + krow;
      uint4 kv = make_uint4(0, 0, 0, 0);
      if (gk < 2308) kv = *(const uint4*)(Kh + (size_t)gk * 64 + c8 * 8);
      *(uint4*)(Ks + krow * 72 + c8 * 8) = kv;
      uint4 vv = *(const uint4*)(VtH + (size_t)krow * 2368 + kt * 64 + c8 * 8);  // krow is d here
      *(uint4*)(Vts + krow * 68 + c8 * 8) = vv;
    }
    __syncthreads();  // staging visible
    short4b pt[4];  // packed P A-frags per jn
#pragma unroll
    for (int jn = 0; jn < 4; jn++) {
      f32x4 st = {};
#pragma unroll
      for (int s = 0; s < 2; s++) {
        short8 kf = *(const short8*)(Ks + (jn * 16 + l15) * 72 + s * 32 + quad * 8);
        st = __builtin_amdgcn_mfma_f32_16x16x32_bf16(kf, qf[s], st, 0, 0, 0);
      }
#pragma unroll
      for (int r = 0; r < 4; r++) {
        float p = fexp2(st[r]);  // CS pre-folded into Q
        if (kt == 36 && (jn * 16 + quad * 4 + r) >= 4) p = 0.f;  // keys >= 2308
        lsumT += p;
        pt[jn][r] = bftrunc(p);
      }
    }
    // O += P·V : A = pt (m=lane&15, k=n=quad*4+j), B = Vts rows (d=lane&15, k=n=quad*4+j)
#pragma unroll
    for (int jn = 0; jn < 4; jn++) {
#pragma unroll
      for (int jo = 0; jo < 4; jo++) {
        short4b vf = *(const short4b*)(Vts + (jo * 16 + l15) * 68 + jn * 16 + quad * 4);
        oacc[jo] = __builtin_amdgcn_mfma_f32_16x16x16bf16_1k(pt[jn], vf, oacc[jo], 0, 0, 0);
      }
    }
  }
  // total row sums: quads hold disjoint n-ranges -> reduce across quads (lanes same l15)
  size_t obase = (size_t)(sp * 16 + bh) * 2304;
  {
    float v = lsumT;
    v += __shfl_xor(v, 16);
    v += __shfl_xor(v, 32);
    if (quad == 0) Lbuf[obase + m0 + wave * 16 + l15] = v;
  }
#pragma unroll
  for (int r = 0; r < 4; r++) {
    int row = m0 + wave * 16 + quad * 4 + r;
#pragma unroll
    for (int jo = 0; jo < 4; jo++)
      Opart[(obase + row) * 64 + jo * 16 + l15] = f2bf(oacc[jo][r]);
  }
}

// ---------------- combine 4 splits -> Ot (vectorized); also zeroes GN2 partials ----------------
__global__ __launch_bounds__(256) void combine_kernel(
    const unsigned short* __restrict__ Opart, const float* __restrict__ Lbuf,
    unsigned short* __restrict__ Ot, float* __restrict__ p2s, float* __restrict__ p2q) {
  int t = threadIdx.x;
  if (blockIdx.x == 0 && t < 128) {  // zero 64+64 GN2 accumulators for gemm_out's atomics
    if (t < 64) p2s[t] = 0.f;
    else        p2q[t - 64] = 0.f;
  }
  int rg = blockIdx.x * 16 + (t >> 4);  // global row index 0..36863
  int d4 = (t & 15) * 4;
  int bh = rg / 2304, row = rg - bh * 2304;
  int b = bh >> 3, h = bh & 7;
  float den = 0.f, num[4] = {};
#pragma unroll
  for (int s = 0; s < 4; s++) {
    size_t ri = ((size_t)(s * 16 + bh) * 2304 + row);
    den += Lbuf[ri];
    uint2 pv = *(const uint2*)(Opart + ri * 64 + d4);
    const unsigned short* pp = (const unsigned short*)&pv;
#pragma unroll
    for (int k = 0; k < 4; k++) num[k] += bf2f(pp[k]);
  }
  float rinv = 1.f / den;
  unsigned short ov[4];
#pragma unroll
  for (int k = 0; k < 4; k++) ov[k] = f2bf(num[k] * rinv);
  *(uint2*)(Ot + ((size_t)(b * 2304 + row)) * 512 + h * 64 + d4) = *(uint2*)ov;
}

// ---------------- GEMM2: 64x128 tiles (288 blocks), fused GN2 stats ----------------
__global__ __launch_bounds__(256) void gemm_out_kernel(
    const unsigned short* __restrict__ A, const unsigned short* __restrict__ Bw,
    const float* __restrict__ bias, float* __restrict__ y,
    float* __restrict__ p2s, float* __restrict__ p2q) {
  __shared__ __attribute__((aligned(16))) unsigned short As[64 * 32];
  __shared__ __attribute__((aligned(16))) unsigned short Bs[128 * 32];
  __shared__ float sgrp[8], qgrp[8];
  int m0 = blockIdx.x * 64, o0 = blockIdx.y * 128;
  int tid = threadIdx.x, lane = tid & 63, wave = tid >> 6;
  int quad = lane >> 4, l15 = lane & 15;
  int wm = wave & 1, wn = wave >> 1;
  if (tid < 8) { sgrp[tid] = 0.f; qgrp[tid] = 0.f; }
  f32x4 acc[2][4] = {};
  for (int k0 = 0; k0 < 512; k0 += 32) {
    __syncthreads();
    {
      int row = tid >> 2, cc = tid & 3;
      __builtin_amdgcn_global_load_lds(GPTR(A + (size_t)(m0 + row) * 512 + k0 + cc * 8),
                                       LPTR(As + tid * 8), 16, 0, 0);
    }
#pragma unroll
    for (int c = 0; c < 2; c++) {
      int q = tid + c * 256;
      int row = q >> 2, cc = q & 3;
      __builtin_amdgcn_global_load_lds(GPTR(Bw + (size_t)(o0 + row) * 512 + k0 + cc * 8),
                                       LPTR(Bs + q * 8), 16, 0, 0);
    }
    __syncthreads();
    short8 af[2], bf[4];
#pragma unroll
    for (int i = 0; i < 2; i++) af[i] = *(const short8*)(As + (wm * 32 + i * 16 + l15) * 32 + quad * 8);
#pragma unroll
    for (int j = 0; j < 4; j++) bf[j] = *(const short8*)(Bs + (wn * 64 + j * 16 + l15) * 32 + quad * 8);
#pragma unroll
    for (int i = 0; i < 2; i++)
#pragma unroll
      for (int j = 0; j < 4; j++)
        acc[i][j] = __builtin_amdgcn_mfma_f32_16x16x32_bf16(af[i], bf[j], acc[i][j], 0, 0, 0);
  }
  float ss[4] = {}, qq[4] = {};
#pragma unroll
  for (int i = 0; i < 2; i++) {
#pragma unroll
    for (int j = 0; j < 4; j++) {
      int colo = o0 + wn * 64 + j * 16 + l15;
      float bb = bias[colo];
#pragma unroll
      for (int reg = 0; reg < 4; reg++) {
        int m = m0 + wm * 32 + i * 16 + quad * 4 + reg;
        float v = acc[i][j][reg] + bb;
        y[(size_t)m * 512 + colo] = v;
        ss[j] += v;
        qq[j] += v * v;
      }
    }
  }
#pragma unroll
  for (int j = 0; j < 4; j++) {
#pragma unroll
    for (int o = 1; o < 64; o <<= 1) { ss[j] += __shfl_xor(ss[j], o); qq[j] += __shfl_xor(qq[j], o); }
  }
  if (lane == 0) {
#pragma unroll
    for (int j = 0; j < 4; j++) {
      atomicAdd(&sgrp[wn * 4 + j], ss[j]);
      atomicAdd(&qgrp[wn * 4 + j], qq[j]);
    }
  }
  __syncthreads();
  if (tid < 8) {
    int b = (m0 >= 2304) ? 1 : 0;
    int g = b * 32 + (o0 >> 4) + tid;
    atomicAdd(&p2s[g], sgrp[tid]);
    atomicAdd(&p2q[g], qgrp[tid]);
  }
}

// ---------------- GN2 normalize + transpose to (B,C,N) ----------------
__global__ __launch_bounds__(256) void gn2_final_kernel(const float* __restrict__ y,
    const float* __restrict__ gw, const float* __restrict__ gb,
    const float* __restrict__ p2s, const float* __restrict__ p2q,
    float* __restrict__ out) {
  __shared__ float tile[32][33];
  int n0 = blockIdx.x * 32, c0 = blockIdx.y * 32, b = blockIdx.z;
  int g0 = c0 >> 4;
  float mu2[2], rs2[2];
#pragma unroll
  for (int gg = 0; gg < 2; gg++) {
    float s = p2s[b * 32 + g0 + gg], q = p2q[b * 32 + g0 + gg];
    float mu = s / 36864.f;
    float var = q / 36864.f - mu * mu;
    mu2[gg] = mu;
    rs2[gg] = rsqrtf(var + 1e-5f);
  }
  int tx = threadIdx.x & 31, ty = threadIdx.x >> 5;
#pragma unroll
  for (int r = 0; r < 4; r++) {
    int n = n0 + ty + r * 8;
    tile[ty + r * 8][tx] = y[((size_t)(b * 2304 + n)) * 512 + c0 + tx];
  }
  __syncthreads();
#pragma unroll
  for (int r = 0; r < 4; r++) {
    int c = c0 + ty + r * 8;
    int gg = (ty + r * 8) >> 4;
    float v = tile[tx][ty + r * 8];
    out[((size_t)(b * 512 + c)) * 2304 + n0 + tx] = (v - mu2[gg]) * rs2[gg] * gw[c] + gb[c];
  }
}

extern "C" void kernel_launch(void* const* d_in, const int* in_sizes, int n_in,
                              void* d_out, int out_size, void* d_ws, size_t ws_size,
                              hipStream_t stream) {
  const float* x     = (const float*)d_in[0];
  const float* gn1w  = (const float*)d_in[1];
  const float* gn1b  = (const float*)d_in[2];
  const float* wqkv  = (const float*)d_in[3];
  const float* memkv = (const float*)d_in[4];
  const float* wout  = (const float*)d_in[5];
  const float* bout  = (const float*)d_in[6];
  const float* gn2w  = (const float*)d_in[7];
  const float* gn2b  = (const float*)d_in[8];
  float* out = (float*)d_out;

  char* ws = (char*)d_ws;
  float2* part1        = (float2*)(ws + 0);                 //   4,096
  float* p2s           = (float*)(ws + 4096);               //     256
  float* p2q           = (float*)(ws + 4352);               //     256
  unsigned short* wqB  = (unsigned short*)(ws + 69632);     // 1,572,864
  unsigned short* woB  = (unsigned short*)(ws + 1642496);   //   524,288
  unsigned short* tB   = (unsigned short*)(ws + 2166784);   // 4,718,592
  unsigned short* Qb   = (unsigned short*)(ws + 6885376);   // 4,718,592
  unsigned short* Kb   = (unsigned short*)(ws + 11603968);  // 4,726,784
  unsigned short* Ot   = (unsigned short*)(ws + 21057536);  // 4,718,592
  float* y             = (float*)(ws + 25776128);           // 9,437,184
  unsigned short* Vt   = (unsigned short*)(ws + 35213312);  // 4,849,664
  unsigned short* Opart= (unsigned short*)(ws + 40062976);  // 18,874,368
  float* Lbuf          = (float*)(ws + 58937344);           //   589,824
  // total workspace use: 59,527,168 bytes

  gn1_stats_kernel<<<512, 256, 0, stream>>>(x, part1);
  tnorm_prep_kernel<<<6432, 256, 0, stream>>>(x, gn1w, gn1b, part1, tB,
                                              wqkv, wout, memkv, wqB, woB, Kb, Vt);
  gemm_qkv_kernel<<<dim3(72, 12), 256, 0, stream>>>(tB, wqB, Qb, Kb, Vt);
  attn_kernel<<<dim3(36, 16, 4), 256, 0, stream>>>(Qb, Kb, Vt, Opart, Lbuf);
  combine_kernel<<<2304, 256, 0, stream>>>(Opart, Lbuf, Ot, p2s, p2q);
  gemm_out_kernel<<<dim3(72, 4), 256, 0, stream>>>(Ot, woB, bout, y, p2s, p2q);
  gn2_final_kernel<<<dim3(72, 16, 2), 256, 0, stream>>>(y, gn2w, gn2b, p2s, p2q, out);
}